// Round 3
// baseline (507.994 us; speedup 1.0000x reference)
//
#include <hip/hip_runtime.h>
#include <hip/hip_cooperative_groups.h>
#include <cfloat>

namespace cg = cooperative_groups;

// Shapes (fixed): x = [32, 1, 8192, 256] fp32, out = [32, 1, 4096, 256] fp32
#define BATCH     32
#define H_IN      8192
#define H_OUT     4096
#define W4        64                    // 256 floats as float4
#define BLK_PER_B 16
#define NBLOCKS   (BATCH * BLK_PER_B)   // 512 blocks = exactly 2/CU co-resident
#define ROWS_BLK  (H_OUT / BLK_PER_B)   // 256 pooled rows per block
#define CH        (ROWS_BLK / 4)        // 64 pooled rows per thread (4 waves)
#define NLDS      16                    // pooled float4/thread kept in LDS (64 KiB/block)
#define NREG      (CH - NLDS)           // 48 pooled float4/thread kept in VGPRs (192 regs)

typedef float f32x4 __attribute__((ext_vector_type(4)));

__device__ __forceinline__ f32x4 max3_f4(f32x4 a, f32x4 b, f32x4 c) {
    f32x4 m;
    m.x = fmaxf(a.x, fmaxf(b.x, c.x));
    m.y = fmaxf(a.y, fmaxf(b.y, c.y));
    m.z = fmaxf(a.z, fmaxf(b.z, c.z));
    m.w = fmaxf(a.w, fmaxf(b.w, c.w));
    return m;
}

// ---------------------------------------------------------------------------
// Fused cooperative kernel: pool -> on-chip (VGPR+LDS) -> grid sync ->
// stats -> normalize -> single nontemporal write. HBM traffic = 268 MB read
// + 134 MB write (the floor). Grid: 512 blocks x 256 threads, exactly
// co-resident (LDS 64 KiB -> 2 blocks/CU; __launch_bounds__ caps VGPR at 256).
// ---------------------------------------------------------------------------
__global__ __launch_bounds__(256, 2) void fused_pool_norm(
        const float* __restrict__ x, float* __restrict__ out,
        float* __restrict__ pmin, float* __restrict__ pmax) {
    const int bid   = blockIdx.x;
    const int batch = bid >> 4;              // / BLK_PER_B
    const int blk   = bid & 15;
    const int tid   = threadIdx.x;
    const int w4    = tid & 63;              // float4 column
    const int rg    = tid >> 6;              // wave index 0..3
    const int h0    = blk * ROWS_BLK + rg * CH;

    __shared__ f32x4 lds4[NLDS * 256];       // 64 KiB: pooled rows 0..15 of each thread
    __shared__ float smax[4], smin[4];
    __shared__ float s_mn, s_inv;

    const f32x4* xin = (const f32x4*)x + (size_t)batch * H_IN * W4 + w4;

    float lmin = FLT_MAX, lmax = -FLT_MAX;
    f32x4 v[NREG];                           // pooled rows 16..63, register-resident

    f32x4 prev;
    const int r0 = 2 * h0 - 1;
    if (r0 >= 0) prev = xin[(size_t)r0 * W4];
    else         prev = (f32x4){-FLT_MAX, -FLT_MAX, -FLT_MAX, -FLT_MAX};

    // Phase 1a: pooled rows i = 0..15 -> LDS (runtime index OK).
    #pragma unroll 4
    for (int i = 0; i < NLDS; ++i) {
        f32x4 a = xin[(size_t)(2 * (h0 + i)) * W4];
        f32x4 c = xin[(size_t)(2 * (h0 + i) + 1) * W4];
        f32x4 m = max3_f4(prev, a, c);
        prev = c;
        lmax = fmaxf(lmax, fmaxf(fmaxf(m.x, m.y), fmaxf(m.z, m.w)));
        lmin = fminf(lmin, fminf(fminf(m.x, m.y), fminf(m.z, m.w)));
        lds4[i * 256 + tid] = m;             // contiguous per wave: conflict-free
    }

    // Phase 1b: pooled rows i = 16..63 -> registers (full unroll: static idx).
    #pragma unroll
    for (int j = 0; j < NREG; ++j) {
        const int i = NLDS + j;
        f32x4 a = xin[(size_t)(2 * (h0 + i)) * W4];
        f32x4 c = xin[(size_t)(2 * (h0 + i) + 1) * W4];
        f32x4 m = max3_f4(prev, a, c);
        prev = c;
        lmax = fmaxf(lmax, fmaxf(fmaxf(m.x, m.y), fmaxf(m.z, m.w)));
        lmin = fminf(lmin, fminf(fminf(m.x, m.y), fminf(m.z, m.w)));
        v[j] = m;
    }

    // Block min/max partial.
    #pragma unroll
    for (int off = 32; off > 0; off >>= 1) {
        lmax = fmaxf(lmax, __shfl_down(lmax, off, 64));
        lmin = fminf(lmin, __shfl_down(lmin, off, 64));
    }
    if ((tid & 63) == 0) { smax[rg] = lmax; smin[rg] = lmin; }
    __syncthreads();
    if (tid == 0) {
        float bmax = fmaxf(fmaxf(smax[0], smax[1]), fmaxf(smax[2], smax[3]));
        float bmin = fminf(fminf(smin[0], smin[1]), fminf(smin[2], smin[3]));
        // Agent-scope atomic stores: guaranteed visible across XCDs after sync.
        __hip_atomic_store(&pmax[bid], bmax, __ATOMIC_RELEASE, __HIP_MEMORY_SCOPE_AGENT);
        __hip_atomic_store(&pmin[bid], bmin, __ATOMIC_RELEASE, __HIP_MEMORY_SCOPE_AGENT);
    }

    cg::this_grid().sync();

    // Per-block reduction of this batch's 16 partials (agent-scope loads).
    if (tid < 64) {
        float mn = (tid < BLK_PER_B)
            ? __hip_atomic_load(&pmin[batch * BLK_PER_B + tid], __ATOMIC_ACQUIRE, __HIP_MEMORY_SCOPE_AGENT)
            : FLT_MAX;
        float mx = (tid < BLK_PER_B)
            ? __hip_atomic_load(&pmax[batch * BLK_PER_B + tid], __ATOMIC_ACQUIRE, __HIP_MEMORY_SCOPE_AGENT)
            : -FLT_MAX;
        #pragma unroll
        for (int off = 8; off > 0; off >>= 1) {
            mn = fminf(mn, __shfl_down(mn, off, 64));
            mx = fmaxf(mx, __shfl_down(mx, off, 64));
        }
        if (tid == 0) { s_mn = mn; s_inv = 1.0f / (mx - mn); }
    }
    __syncthreads();
    const float mn  = s_mn;
    const float inv = s_inv;

    // Phase 2: normalize from on-chip storage, single nontemporal write.
    f32x4* po = (f32x4*)out + ((size_t)batch * H_OUT + h0) * W4 + w4;
    #pragma unroll 4
    for (int i = 0; i < NLDS; ++i) {
        f32x4 m = lds4[i * 256 + tid];
        f32x4 r = { (m.x - mn) * inv, (m.y - mn) * inv,
                    (m.z - mn) * inv, (m.w - mn) * inv };
        __builtin_nontemporal_store(r, po + (size_t)i * W4);
    }
    #pragma unroll
    for (int j = 0; j < NREG; ++j) {
        f32x4 m = v[j];
        f32x4 r = { (m.x - mn) * inv, (m.y - mn) * inv,
                    (m.z - mn) * inv, (m.w - mn) * inv };
        __builtin_nontemporal_store(r, po + (size_t)(NLDS + j) * W4);
    }
}

// ---------------------------------------------------------------------------
// Fallback path (proven R2 structure, 427 µs) if cooperative launch is
// rejected by the runtime/graph-capture.
// ---------------------------------------------------------------------------
#define FB_BLK_PER_B 64
#define FB_CH        16

__global__ __launch_bounds__(256) void pool_store_partial(
        const float* __restrict__ x, float* __restrict__ out,
        float* __restrict__ partial_min, float* __restrict__ partial_max) {
    const int batch = blockIdx.x >> 6;
    const int blk   = blockIdx.x & 63;
    const int tid   = threadIdx.x;
    const int w4    = tid & 63;
    const int rg    = tid >> 6;
    const int h0    = blk * (4 * FB_CH) + rg * FB_CH;

    const f32x4* xin = (const f32x4*)x + (size_t)batch * H_IN * W4 + w4;
    f32x4*       po  = (f32x4*)out + ((size_t)batch * H_OUT + h0) * W4 + w4;

    float lmin = FLT_MAX, lmax = -FLT_MAX;

    f32x4 prev;
    const int r0 = 2 * h0 - 1;
    if (r0 >= 0) prev = xin[(size_t)r0 * W4];
    else         prev = (f32x4){-FLT_MAX, -FLT_MAX, -FLT_MAX, -FLT_MAX};

    #pragma unroll 4
    for (int i = 0; i < FB_CH; ++i) {
        const int r = 2 * (h0 + i);
        f32x4 a = xin[(size_t)r * W4];
        f32x4 c = xin[(size_t)(r + 1) * W4];
        f32x4 m = max3_f4(prev, a, c);
        po[(size_t)i * W4] = m;
        prev = c;
        lmax = fmaxf(lmax, fmaxf(fmaxf(m.x, m.y), fmaxf(m.z, m.w)));
        lmin = fminf(lmin, fminf(fminf(m.x, m.y), fminf(m.z, m.w)));
    }

    #pragma unroll
    for (int off = 32; off > 0; off >>= 1) {
        lmax = fmaxf(lmax, __shfl_down(lmax, off, 64));
        lmin = fminf(lmin, __shfl_down(lmin, off, 64));
    }
    __shared__ float smax[4], smin[4];
    if ((tid & 63) == 0) { smax[rg] = lmax; smin[rg] = lmin; }
    __syncthreads();
    if (tid == 0) {
        float bmax = smax[0], bmin = smin[0];
        #pragma unroll
        for (int i = 1; i < 4; ++i) {
            bmax = fmaxf(bmax, smax[i]);
            bmin = fminf(bmin, smin[i]);
        }
        partial_max[blockIdx.x] = bmax;
        partial_min[blockIdx.x] = bmin;
    }
}

__global__ __launch_bounds__(256) void finish_normalize(
        float* __restrict__ out,
        const float* __restrict__ pmin, const float* __restrict__ pmax) {
    const int batch = blockIdx.x >> 6;
    const int blk   = blockIdx.x & 63;
    const int tid   = threadIdx.x;

    __shared__ float s_mn, s_inv;
    if (tid < 64) {
        float mn = pmin[batch * FB_BLK_PER_B + tid];
        float mx = pmax[batch * FB_BLK_PER_B + tid];
        #pragma unroll
        for (int off = 32; off > 0; off >>= 1) {
            mn = fminf(mn, __shfl_down(mn, off, 64));
            mx = fmaxf(mx, __shfl_down(mx, off, 64));
        }
        if (tid == 0) { s_mn = mn; s_inv = 1.0f / (mx - mn); }
    }
    __syncthreads();
    const float mn  = s_mn;
    const float inv = s_inv;

    f32x4* p = (f32x4*)out + (size_t)batch * (H_OUT * W4) + (size_t)blk * 4096;
    #pragma unroll 4
    for (int j = 0; j < 16; ++j) {
        const int idx = tid + j * 256;
        f32x4 v = p[idx];
        v.x = (v.x - mn) * inv;
        v.y = (v.y - mn) * inv;
        v.z = (v.z - mn) * inv;
        v.w = (v.w - mn) * inv;
        __builtin_nontemporal_store(v, p + idx);
    }
}

extern "C" void kernel_launch(void* const* d_in, const int* in_sizes, int n_in,
                              void* d_out, int out_size, void* d_ws, size_t ws_size,
                              hipStream_t stream) {
    const float* x   = (const float*)d_in[0];
    float*       out = (float*)d_out;
    float*       ws  = (float*)d_ws;

    float* pmin = ws;                  // NBLOCKS floats (coop) / 2048 (fallback)
    float* pmax = ws + 2048;

    void* args[] = { (void*)&x, (void*)&out, (void*)&pmin, (void*)&pmax };
    hipError_t err = hipLaunchCooperativeKernel(
        (const void*)fused_pool_norm, dim3(NBLOCKS), dim3(256), args, 0, stream);

    if (err != hipSuccess) {
        // Fallback: proven two-kernel path.
        pool_store_partial<<<BATCH * FB_BLK_PER_B, 256, 0, stream>>>(x, out, pmin, pmax);
        finish_normalize<<<BATCH * FB_BLK_PER_B, 256, 0, stream>>>(out, pmin, pmax);
    }
}